// Round 1
// baseline (18955.695 us; speedup 1.0000x reference)
//
#include <hip/hip_runtime.h>
#include <math.h>

// Problem constants (fixed by the reference)
constexpr int SVEC = 576;    // N_CH * SIZE * SIZE = 9*64
constexpr int INF  = 2304;   // 4 * SVEC  (MLP input)
constexpr int HID  = 256;
constexpr int OUTF = 1152;   // 2 * SVEC  (MLP output)
constexpr int TS   = 20;     // T

// ---------------- init: S chunks [x|p|y|z] all = x0 = [noisy, zeros] ----------
__global__ __launch_bounds__(256) void k_init_S(float* __restrict__ S,
                                                const float* __restrict__ noisy,
                                                int total /* B*2304 */) {
    int i = blockIdx.x * 256 + threadIdx.x;
    if (i >= total) return;
    int sample = i / INF;
    int j = i - sample * INF;       // 0..2303
    int jj = j % SVEC;              // position within chunk
    S[i] = (jj < 64) ? noisy[sample * 64 + jj] : 0.f;
}

__global__ __launch_bounds__(256) void k_zero(float* __restrict__ p, int n) {
    int i = blockIdx.x * 256 + threadIdx.x;
    if (i < n) p[i] = 0.f;
}

// ---------------- elementwise FBS step (in-place on S) -----------------------
// S chunks: [0]=x  [1]=p_prev  [2]=y_prev  [3]=z_prev
// writes:   [0]=x_new [1]=pr   [2]=y      [3]=z     (== next MLP input order)
__global__ __launch_bounds__(256) void k_fbs(float* __restrict__ S,
                                             const float* __restrict__ uv,
                                             const float* __restrict__ alpha_p,
                                             float* __restrict__ res2_p,
                                             float* __restrict__ delta_p,
                                             float an, int total /* B*576 */) {
    int i = blockIdx.x * 256 + threadIdx.x;
    float r = 0.f, d = 0.f;
    if (i < total) {
        int sample = i / SVEC;
        int j = i - sample * SVEC;
        int base = sample * INF + j;
        float x  = S[base];
        float p  = S[base + SVEC];
        float y0 = S[base + 2 * SVEC];
        float z0 = S[base + 3 * SVEC];
        float alpha = *alpha_p;
        float u = alpha * uv[sample * OUTF + j];
        float v = alpha * uv[sample * OUTF + SVEC + j];
        // schedule: gamma=1, lam=1, ab_n = a_n = an
        float y  = x + an * (y0 - x) + u;
        float dz = an * (z0 - p);
        float z  = x + an * (p - x) + dz + u + v;
        float zm = z - y;                       // z - gam*Cy, Cy = y
        float t  = fabsf(zm) - 0.1f;            // gam*TAU = 0.1
        float pr = (t > 0.f) ? copysignf(t, zm) : 0.f;
        float xn = x + (pr - z) + dz;
        S[base]            = xn;
        S[base + SVEC]     = pr;
        S[base + 2 * SVEC] = y;
        S[base + 3 * SVEC] = z;
        float e1 = pr - y; r = e1 * e1;
        float e2 = xn - z; d = e2 * e2;
    }
    // block reduction -> one atomic per block
    #pragma unroll
    for (int off = 32; off > 0; off >>= 1) {
        r += __shfl_down(r, off);
        d += __shfl_down(d, off);
    }
    __shared__ float sr[4], sd[4];
    int lane = threadIdx.x & 63, wid = threadIdx.x >> 6;
    if (lane == 0) { sr[wid] = r; sd[wid] = d; }
    __syncthreads();
    if (threadIdx.x == 0) {
        atomicAdd(res2_p,  sr[0] + sr[1] + sr[2] + sr[3]);
        atomicAdd(delta_p, sd[0] + sd[1] + sd[2] + sd[3]);
    }
}

// ---------------- f32 GEMM: C[M,N] = A[M,K] @ W[K,N] + bias, opt ReLU, opt Q --
// 64x64 block tile, BK=16, 256 threads, 4x4 per thread.
template <bool RELU, bool QACC>
__global__ __launch_bounds__(256) void k_gemm(const float* __restrict__ A,
                                              const float* __restrict__ W,
                                              const float* __restrict__ bias,
                                              float* __restrict__ C,
                                              int K, int N,
                                              float* __restrict__ qaccum) {
    __shared__ float As[16][64];   // transposed A tile: As[k][m]
    __shared__ float Bs[16][64];
    const int tid = threadIdx.x;
    const int m0 = blockIdx.x * 64;
    const int n0 = blockIdx.y * 64;
    const int tx = tid & 15, ty = tid >> 4;          // 16x16 thread grid
    const int ar = tid >> 2, ak = (tid & 3) * 4;     // A stage: row, k-quad
    const int br = tid >> 4, bc = (tid & 15) * 4;    // B stage: k-row, col-quad

    const float* Ap = A + (m0 + ar) * K + ak;
    const float* Wp = W + br * N + n0 + bc;

    float acc[4][4] = {};

    for (int k0 = 0; k0 < K; k0 += 16) {
        float4 av = *(const float4*)(Ap + k0);
        float4 bv = *(const float4*)(Wp + k0 * N);
        As[ak + 0][ar] = av.x;
        As[ak + 1][ar] = av.y;
        As[ak + 2][ar] = av.z;
        As[ak + 3][ar] = av.w;
        *(float4*)&Bs[br][bc] = bv;
        __syncthreads();
        #pragma unroll
        for (int kk = 0; kk < 16; ++kk) {
            float4 a = *(const float4*)&As[kk][ty * 4];
            float4 b = *(const float4*)&Bs[kk][tx * 4];
            acc[0][0] += a.x * b.x; acc[0][1] += a.x * b.y; acc[0][2] += a.x * b.z; acc[0][3] += a.x * b.w;
            acc[1][0] += a.y * b.x; acc[1][1] += a.y * b.y; acc[1][2] += a.y * b.z; acc[1][3] += a.y * b.w;
            acc[2][0] += a.z * b.x; acc[2][1] += a.z * b.y; acc[2][2] += a.z * b.z; acc[2][3] += a.z * b.w;
            acc[3][0] += a.w * b.x; acc[3][1] += a.w * b.y; acc[3][2] += a.w * b.z; acc[3][3] += a.w * b.w;
        }
        __syncthreads();
    }

    float4 bb = *(const float4*)&bias[n0 + tx * 4];
    float q = 0.f;
    #pragma unroll
    for (int i = 0; i < 4; ++i) {
        float4 c;
        c.x = acc[i][0] + bb.x;
        c.y = acc[i][1] + bb.y;
        c.z = acc[i][2] + bb.z;
        c.w = acc[i][3] + bb.w;
        if (RELU) {
            c.x = fmaxf(c.x, 0.f); c.y = fmaxf(c.y, 0.f);
            c.z = fmaxf(c.z, 0.f); c.w = fmaxf(c.w, 0.f);
        }
        if (QACC) q += c.x * c.x + c.y * c.y + c.z * c.z + c.w * c.w;
        *(float4*)&C[(m0 + ty * 4 + i) * N + n0 + tx * 4] = c;
    }

    if (QACC) {
        #pragma unroll
        for (int off = 32; off > 0; off >>= 1) q += __shfl_down(q, off);
        __shared__ float sq[4];
        int lane = tid & 63, wid = tid >> 6;
        if (lane == 0) sq[wid] = q;
        __syncthreads();
        if (tid == 0) atomicAdd(qaccum, sq[0] + sq[1] + sq[2] + sq[3]);
    }
}

// ---------------- per-step scalar chain: alpha + residual output -------------
// red layout: res2[0..19] | delta[20..39] | Q[40..59] | alpha[60]
__global__ void k_alpha(const float* __restrict__ red, float* __restrict__ alpha,
                        float* __restrict__ res_out, int n) {
    float Q      = 1.5f * red[40 + n] + 1e-12f;          // lpm * (sum u^2 + sum v^2)
    float budget = 0.99f * fmaxf(red[20 + n], 0.f);      // ZETA * max(delta,0)
    *alpha = sqrtf(fminf(budget / Q, 1.f));
    res_out[n] = sqrtf(red[n] + 1e-12f);
}

// ---------------- final output: p_final = S chunk 1 --------------------------
__global__ __launch_bounds__(256) void k_copy_p(const float* __restrict__ S,
                                                float* __restrict__ outp,
                                                int total /* B*576 */) {
    int i = blockIdx.x * 256 + threadIdx.x;
    if (i >= total) return;
    int sample = i / SVEC;
    int j = i - sample * SVEC;
    outp[i] = S[sample * INF + SVEC + j];
}

extern "C" void kernel_launch(void* const* d_in, const int* in_sizes, int n_in,
                              void* d_out, int out_size, void* d_ws, size_t ws_size,
                              hipStream_t stream) {
    const float* noisy = (const float*)d_in[0];
    const float* W1 = (const float*)d_in[1];
    const float* b1 = (const float*)d_in[2];
    const float* W2 = (const float*)d_in[3];
    const float* b2 = (const float*)d_in[4];
    const float* W3 = (const float*)d_in[5];
    const float* b3 = (const float*)d_in[6];
    const int B = in_sizes[0] / 64;   // 16384

    // workspace layout (floats)
    float* S   = (float*)d_ws;                 // [B, 2304]
    float* uv  = S  + (size_t)B * INF;         // [B, 1152]  (u_raw|v_raw)
    float* h1  = uv + (size_t)B * OUTF;        // [B, 256]
    float* h2  = h1 + (size_t)B * HID;         // [B, 256]
    float* red = h2 + (size_t)B * HID;         // 61 scalars
    float* alpha = red + 60;

    float* p_out   = (float*)d_out;            // [B, 576]
    float* res_out = p_out + (size_t)B * SVEC; // [20]

    const int totS  = B * INF;
    const int totV  = B * SVEC;
    const int totUV = B * OUTF;

    k_init_S<<<(totS + 255) / 256, 256, 0, stream>>>(S, noisy, totS);
    k_zero<<<(totUV + 255) / 256, 256, 0, stream>>>(uv, totUV);
    k_zero<<<1, 64, 0, stream>>>(red, 61);

    dim3 g12(B / 64, HID / 64);    // 256 x 4
    dim3 g3 (B / 64, OUTF / 64);   // 256 x 18

    for (int n = 0; n < TS; ++n) {
        float an = (float)n / ((float)n + 3.0f);
        k_fbs<<<(totV + 255) / 256, 256, 0, stream>>>(S, uv, alpha,
                                                      red + n, red + 20 + n, an, totV);
        k_gemm<true,  false><<<g12, 256, 0, stream>>>(S,  W1, b1, h1, INF, HID, nullptr);
        k_gemm<true,  false><<<g12, 256, 0, stream>>>(h1, W2, b2, h2, HID, HID, nullptr);
        k_gemm<false, true ><<<g3,  256, 0, stream>>>(h2, W3, b3, uv, HID, OUTF, red + 40 + n);
        k_alpha<<<1, 1, 0, stream>>>(red, alpha, res_out, n);
    }
    k_copy_p<<<(totV + 255) / 256, 256, 0, stream>>>(S, p_out, totV);
}

// Round 3
// 6207.274 us; speedup vs baseline: 3.0538x; 3.0538x over previous
//
#include <hip/hip_runtime.h>
#include <math.h>

constexpr int SVEC = 576;    // N_CH * 64
constexpr int INF  = 2304;   // 4 * SVEC
constexpr int HID  = 256;
constexpr int OUTF = 1152;   // 2 * SVEC
constexpr int TS   = 20;

// ---------- helpers ----------------------------------------------------------
__device__ __forceinline__ ushort f2bf(float f) {    // RNE f32->bf16
    union { float f; unsigned u; } a; a.f = f;
    unsigned r = a.u + 0x7fff + ((a.u >> 16) & 1);
    return (ushort)(r >> 16);
}

__device__ __forceinline__ void gload_lds16(const void* g, void* l) {
    __builtin_amdgcn_global_load_lds(
        (const __attribute__((address_space(1))) void*)g,
        (__attribute__((address_space(3))) void*)l, 16, 0, 0);
}

typedef short  s16x8 __attribute__((ext_vector_type(8)));
typedef float  f32x4 __attribute__((ext_vector_type(4)));

// ---------- init: S = [x|p|y|z] all = [noisy, 0...] --------------------------
__global__ __launch_bounds__(256) void k_init(float4* __restrict__ S4,
                                              const float4* __restrict__ noisy4,
                                              int total4 /* B*576 */) {
    int i = blockIdx.x * 256 + threadIdx.x;
    if (i >= total4) return;
    int sample = i / 576;
    int j = i - sample * 576;
    int jc = j % 144;                       // pos within one chunk (float4 units)
    float4 v = make_float4(0.f, 0.f, 0.f, 0.f);
    if (jc < 16) v = noisy4[sample * 16 + jc];
    S4[i] = v;
}

__global__ __launch_bounds__(128) void k_zero(float* __restrict__ p, int n) {
    int i = blockIdx.x * 128 + threadIdx.x;
    if (i < n) p[i] = 0.f;
}

// ---------- weight transpose + bf16 convert: Wt[n*K+k] = W[k*N+n] ------------
__global__ __launch_bounds__(256) void k_wt(const float* __restrict__ W,
                                            ushort* __restrict__ Wt,
                                            int K, int N, int total) {
    int i = blockIdx.x * 256 + threadIdx.x;
    if (i >= total) return;
    int n = i / K, k = i - n * K;
    Wt[i] = f2bf(W[(size_t)k * N + n]);
}

// ---------- elementwise FBS step (in-place on S), bucketized reductions ------
// S chunks: [x|p_prev|y_prev|z_prev] -> [x_new|pr|y|z]  (== MLP input order)
__global__ __launch_bounds__(256) void k_fbs(float4* __restrict__ S4,
                                             const float4* __restrict__ uv4,
                                             const float* __restrict__ alpha_p,
                                             float* __restrict__ rbuck,
                                             float* __restrict__ dbuck,
                                             float an, int total4 /* B*144 */) {
    int i = blockIdx.x * 256 + threadIdx.x;
    float r = 0.f, d = 0.f;
    if (i < total4) {
        int sample = i / 144;
        int j = i - sample * 144;
        size_t base = (size_t)sample * 576 + j;
        float4 x4 = S4[base], p4 = S4[base + 144], y4 = S4[base + 288], z4 = S4[base + 432];
        size_t ub = (size_t)sample * 288 + j;
        float al = *alpha_p;
        float4 u4 = uv4[ub], v4 = uv4[ub + 144];
        float4 xn4, pr4, yy4, zz4;
        const float* X = (const float*)&x4; const float* P = (const float*)&p4;
        const float* Y0 = (const float*)&y4; const float* Z0 = (const float*)&z4;
        const float* U = (const float*)&u4; const float* V = (const float*)&v4;
        float* XN = (float*)&xn4; float* PR = (float*)&pr4;
        float* YY = (float*)&yy4; float* ZZ = (float*)&zz4;
        #pragma unroll
        for (int c = 0; c < 4; ++c) {
            float x = X[c], p = P[c], y0 = Y0[c], z0 = Z0[c];
            float u = al * U[c], v = al * V[c];
            float y  = x + an * (y0 - x) + u;
            float dz = an * (z0 - p);
            float z  = x + an * (p - x) + dz + u + v;
            float zm = z - y;
            float t  = fabsf(zm) - 0.1f;
            float pr = (t > 0.f) ? copysignf(t, zm) : 0.f;
            float xn = x + (pr - z) + dz;
            XN[c] = xn; PR[c] = pr; YY[c] = y; ZZ[c] = z;
            float e1 = pr - y; r += e1 * e1;
            float e2 = xn - z; d += e2 * e2;
        }
        S4[base] = xn4; S4[base + 144] = pr4; S4[base + 288] = yy4; S4[base + 432] = zz4;
    }
    #pragma unroll
    for (int off = 32; off > 0; off >>= 1) {
        r += __shfl_down(r, off);
        d += __shfl_down(d, off);
    }
    __shared__ float sr[4], sd[4];
    int lane = threadIdx.x & 63, wid = threadIdx.x >> 6;
    if (lane == 0) { sr[wid] = r; sd[wid] = d; }
    __syncthreads();
    if (threadIdx.x == 0) {
        int bk = blockIdx.x & 31;
        atomicAdd(&rbuck[bk], sr[0] + sr[1] + sr[2] + sr[3]);
        atomicAdd(&dbuck[bk], sd[0] + sd[1] + sd[2] + sd[3]);
    }
}

// ---------- bf16 MFMA GEMM: C[M,N] = A[M,K] @ Wt[N,K]^T + bias ---------------
// 256 thr = 4 waves (2x2), tile 128x128, BK=32, 16x16x32 bf16 MFMA.
// AF32: A is f32, converted to bf16 during LDS staging (VGPR path).
// NB: n-blocks per m-row; 1-D grid with same-A blocks adjacent for L2 reuse.
template <bool AF32, bool RELU, bool QACC, bool BF16OUT, int NB>
__global__ __launch_bounds__(256) void k_gemm(const void* __restrict__ Avoid,
                                              const ushort* __restrict__ Wt,
                                              const float* __restrict__ bias,
                                              void* __restrict__ Cout,
                                              int K, int N,
                                              float* __restrict__ qbuck) {
    __shared__ ushort As[128 * 32];
    __shared__ ushort Bs[128 * 32];
    const int tid = threadIdx.x;
    const int bx = blockIdx.x;
    const int m0 = (bx / NB) * 128;
    const int n0 = (bx % NB) * 128;
    const int wave = tid >> 6, lane = tid & 63;
    const int wm = (wave & 1) * 64;
    const int wn = (wave >> 1) * 64;
    const int lm = lane & 15, quad = lane >> 4;

    f32x4 acc[4][4];
    #pragma unroll
    for (int i = 0; i < 4; ++i)
        #pragma unroll
        for (int j = 0; j < 4; ++j) acc[i][j] = (f32x4){0.f, 0.f, 0.f, 0.f};

    for (int k0 = 0; k0 < K; k0 += 32) {
        if (AF32) {
            const float* A = (const float*)Avoid;
            #pragma unroll
            for (int c = tid; c < 1024; c += 256) {      // 128 rows x 8 float4
                int rr = c >> 3, kq = (c & 7) << 2;
                float4 av = *(const float4*)(A + (size_t)(m0 + rr) * K + k0 + kq);
                ushort4 b4;
                b4.x = f2bf(av.x); b4.y = f2bf(av.y); b4.z = f2bf(av.z); b4.w = f2bf(av.w);
                *(ushort4*)&As[rr * 32 + kq] = b4;
            }
        } else {
            const ushort* A = (const ushort*)Avoid;
            #pragma unroll
            for (int c = tid; c < 512; c += 256) {       // 128 rows x 4 chunks
                int rr = c >> 2, kq = (c & 3) << 3;
                gload_lds16(A + (size_t)(m0 + rr) * K + k0 + kq, &As[c * 8]);
            }
        }
        #pragma unroll
        for (int c = tid; c < 512; c += 256) {           // 128 rows x 4 chunks
            int rr = c >> 2, kq = (c & 3) << 3;
            gload_lds16(Wt + (size_t)(n0 + rr) * K + k0 + kq, &Bs[c * 8]);
        }
        __syncthreads();
        s16x8 af[4], bfr[4];
        #pragma unroll
        for (int i = 0; i < 4; ++i)
            af[i] = *(const s16x8*)&As[(wm + i * 16 + lm) * 32 + quad * 8];
        #pragma unroll
        for (int j = 0; j < 4; ++j)
            bfr[j] = *(const s16x8*)&Bs[(wn + j * 16 + lm) * 32 + quad * 8];
        #pragma unroll
        for (int i = 0; i < 4; ++i)
            #pragma unroll
            for (int j = 0; j < 4; ++j)
                acc[i][j] = __builtin_amdgcn_mfma_f32_16x16x32_bf16(af[i], bfr[j], acc[i][j], 0, 0, 0);
        __syncthreads();
    }

    float q = 0.f;
    #pragma unroll
    for (int j = 0; j < 4; ++j) {
        int col = n0 + wn + j * 16 + lm;
        float bb = bias[col];
        #pragma unroll
        for (int i = 0; i < 4; ++i) {
            #pragma unroll
            for (int rr = 0; rr < 4; ++rr) {
                int row = m0 + wm + i * 16 + quad * 4 + rr;
                float c = acc[i][j][rr] + bb;
                if (RELU) c = fmaxf(c, 0.f);
                if (QACC) q += c * c;
                if (BF16OUT) ((ushort*)Cout)[(size_t)row * N + col] = f2bf(c);
                else         ((float*)Cout)[(size_t)row * N + col] = c;
            }
        }
    }
    if (QACC) {
        #pragma unroll
        for (int off = 32; off > 0; off >>= 1) q += __shfl_down(q, off);
        __shared__ float sq[4];
        if (lane == 0) sq[wave] = q;
        __syncthreads();
        if (tid == 0) atomicAdd(&qbuck[bx & 31], sq[0] + sq[1] + sq[2] + sq[3]);
    }
}

// ---------- per-step scalars: fold buckets, alpha, residual, re-zero ---------
// red layout: rbuck[0:32] | dbuck[32:64] | qbuck[64:96] | alpha[96]
__global__ void k_alpha(float* __restrict__ red, float* __restrict__ res_out, int n) {
    int t = threadIdx.x;  // 128
    float r = 0.f, d = 0.f, q = 0.f;
    if (t < 32) { r = red[t]; d = red[32 + t]; q = red[64 + t]; }
    #pragma unroll
    for (int off = 16; off > 0; off >>= 1) {
        r += __shfl_down(r, off, 64);
        d += __shfl_down(d, off, 64);
        q += __shfl_down(q, off, 64);
    }
    __syncthreads();                 // all reads done before re-zeroing
    if (t < 96) red[t] = 0.f;
    if (t == 0) {
        float Q = 1.5f * q + 1e-12f;
        float budget = 0.99f * fmaxf(d, 0.f);
        red[96] = sqrtf(fminf(budget / Q, 1.f));   // alpha for next step
        res_out[n] = sqrtf(r + 1e-12f);
    }
}

// ---------- final output: p_final = S chunk 1 --------------------------------
__global__ __launch_bounds__(256) void k_copy_p(const float4* __restrict__ S4,
                                                float4* __restrict__ out4,
                                                int total4 /* B*144 */) {
    int i = blockIdx.x * 256 + threadIdx.x;
    if (i >= total4) return;
    int sample = i / 144;
    int j = i - sample * 144;
    out4[i] = S4[(size_t)sample * 576 + 144 + j];
}

extern "C" void kernel_launch(void* const* d_in, const int* in_sizes, int n_in,
                              void* d_out, int out_size, void* d_ws, size_t ws_size,
                              hipStream_t stream) {
    const float* noisy = (const float*)d_in[0];
    const float* W1 = (const float*)d_in[1];
    const float* b1 = (const float*)d_in[2];
    const float* W2 = (const float*)d_in[3];
    const float* b2 = (const float*)d_in[4];
    const float* W3 = (const float*)d_in[5];
    const float* b3 = (const float*)d_in[6];
    const int B = in_sizes[0] / 64;   // 16384

    // workspace layout (total ~245.2 MB; keep < 256 MiB)
    float*  S   = (float*)d_ws;                         // [B,2304] f32
    float*  uv  = S + (size_t)B * INF;                  // [B,1152] f32
    ushort* h1  = (ushort*)(uv + (size_t)B * OUTF);     // [B,256]  bf16
    ushort* h2  = h1 + (size_t)B * HID;                 // [B,256]  bf16
    ushort* Wt1 = h2 + (size_t)B * HID;                 // [256,2304] bf16
    ushort* Wt2 = Wt1 + (size_t)HID * INF;              // [256,256]  bf16
    ushort* Wt3 = Wt2 + (size_t)HID * HID;              // [1152,256] bf16
    float*  red = (float*)(Wt3 + (size_t)OUTF * HID);   // 97 floats
    float*  alpha = red + 96;

    float* p_out   = (float*)d_out;                     // [B,576]
    float* res_out = p_out + (size_t)B * SVEC;          // [20]

    const int tot4 = B * 144;                           // float4 units per chunk-slot

    k_init<<<(tot4 * 4 + 255) / 256, 256, 0, stream>>>((float4*)S, (const float4*)noisy, tot4 * 4);
    k_zero<<<1, 128, 0, stream>>>(red, 97);
    k_wt<<<(HID * INF + 255) / 256, 256, 0, stream>>>(W1, Wt1, INF, HID, HID * INF);
    k_wt<<<(HID * HID + 255) / 256, 256, 0, stream>>>(W2, Wt2, HID, HID, HID * HID);
    k_wt<<<(OUTF * HID + 255) / 256, 256, 0, stream>>>(W3, Wt3, HID, OUTF, OUTF * HID);

    const int g1 = (B / 128) * 2;    // 256 blocks  (NB=2)
    const int g2 = (B / 128) * 2;    // 256 blocks  (NB=2)
    const int g3 = (B / 128) * 9;    // 1152 blocks (NB=9)

    for (int n = 0; n < TS; ++n) {
        float an = (float)n / ((float)n + 3.0f);
        k_fbs<<<(tot4 + 255) / 256, 256, 0, stream>>>((float4*)S, (const float4*)uv,
                                                      alpha, red, red + 32, an, tot4);
        k_gemm<true,  true,  false, true,  2><<<g1, 256, 0, stream>>>(S,  Wt1, b1, h1, INF, HID, nullptr);
        k_gemm<false, true,  false, true,  2><<<g2, 256, 0, stream>>>(h1, Wt2, b2, h2, HID, HID, nullptr);
        k_gemm<false, false, true,  false, 9><<<g3, 256, 0, stream>>>(h2, Wt3, b3, uv, HID, OUTF, red + 64);
        k_alpha<<<1, 128, 0, stream>>>(red, res_out, n);
    }
    k_copy_p<<<(tot4 + 255) / 256, 256, 0, stream>>>((const float4*)S, (float4*)p_out, tot4);
}

// Round 4
// 4622.498 us; speedup vs baseline: 4.1007x; 1.3428x over previous
//
#include <hip/hip_runtime.h>
#include <math.h>

constexpr int SVEC = 576;    // N_CH * 64
constexpr int INF  = 2304;   // 4 * SVEC
constexpr int HID  = 256;
constexpr int OUTF = 1152;   // 2 * SVEC
constexpr int TS   = 20;

// ---------- helpers ----------------------------------------------------------
__device__ __forceinline__ ushort f2bf(float f) {    // RNE f32->bf16
    union { float f; unsigned u; } a; a.f = f;
    unsigned r = a.u + 0x7fff + ((a.u >> 16) & 1);
    return (ushort)(r >> 16);
}

__device__ __forceinline__ void gload_lds16(const void* g, void* l) {
    __builtin_amdgcn_global_load_lds(
        (const __attribute__((address_space(1))) void*)g,
        (__attribute__((address_space(3))) void*)l, 16, 0, 0);
}

typedef short  s16x8 __attribute__((ext_vector_type(8)));
typedef float  f32x4 __attribute__((ext_vector_type(4)));

// ---------- init: S = [x|p|y|z] all = [noisy, 0...] --------------------------
__global__ __launch_bounds__(256) void k_init(float4* __restrict__ S4,
                                              const float4* __restrict__ noisy4,
                                              int total4 /* B*576 */) {
    int i = blockIdx.x * 256 + threadIdx.x;
    if (i >= total4) return;
    int sample = i / 576;
    int j = i - sample * 576;
    int jc = j % 144;                       // pos within one chunk (float4 units)
    float4 v = make_float4(0.f, 0.f, 0.f, 0.f);
    if (jc < 16) v = noisy4[sample * 16 + jc];
    S4[i] = v;
}

__global__ __launch_bounds__(128) void k_zero(float* __restrict__ p, int n) {
    int i = blockIdx.x * 128 + threadIdx.x;
    if (i < n) p[i] = 0.f;
}

// ---------- weight transpose + bf16 convert: Wt[n*K+k] = W[k*N+n] ------------
__global__ __launch_bounds__(256) void k_wt(const float* __restrict__ W,
                                            ushort* __restrict__ Wt,
                                            int K, int N, int total) {
    int i = blockIdx.x * 256 + threadIdx.x;
    if (i >= total) return;
    int n = i / K, k = i - n * K;
    Wt[i] = f2bf(W[(size_t)k * N + n]);
}

// ---------- elementwise FBS step (in-place on S) -----------------------------
// S chunks: [x|p_prev|y_prev|z_prev] -> [x_new|pr|y|z]  (== MLP input order)
// redprev = scalar slot of previous step (dbuck@32, qbuck@64) -> alpha inline.
// redcur  = this step's slot (rbuck@0, dbuck@32).
__global__ __launch_bounds__(256) void k_fbs(float4* __restrict__ S4,
                                             const float4* __restrict__ uv4,
                                             const float* __restrict__ redprev,
                                             float* __restrict__ redcur,
                                             float an, int total4 /* B*144 */) {
    int i = blockIdx.x * 256 + threadIdx.x;
    bool act = (i < total4);
    float4 x4, p4, y4, z4, u4, v4;
    size_t base = 0;
    if (act) {
        int sample = i / 144;
        int j = i - sample * 144;
        base = (size_t)sample * 576 + j;
        x4 = S4[base]; p4 = S4[base + 144]; y4 = S4[base + 288]; z4 = S4[base + 432];
        size_t ub = (size_t)sample * 288 + j;
        u4 = uv4[ub]; v4 = uv4[ub + 144];
    }
    // inline alpha from previous step's buckets (zeros for step 0)
    __shared__ float s_alpha;
    {
        int t = threadIdx.x;
        if (t < 64) {
            float v = (t < 32) ? redprev[32 + t] : redprev[64 + (t - 32)];
            #pragma unroll
            for (int off = 16; off > 0; off >>= 1) v += __shfl_down(v, off);
            float Q = __shfl(v, 32);
            if (t == 0) {
                float Qs = 1.5f * Q + 1e-12f;
                float b  = 0.99f * fmaxf(v, 0.f);
                s_alpha = sqrtf(fminf(b / Qs, 1.f));
            }
        }
    }
    __syncthreads();
    float al = s_alpha;
    float r = 0.f, d = 0.f;
    if (act) {
        float4 xn4, pr4, yy4, zz4;
        const float* X = (const float*)&x4; const float* P = (const float*)&p4;
        const float* Y0 = (const float*)&y4; const float* Z0 = (const float*)&z4;
        const float* U = (const float*)&u4; const float* V = (const float*)&v4;
        float* XN = (float*)&xn4; float* PR = (float*)&pr4;
        float* YY = (float*)&yy4; float* ZZ = (float*)&zz4;
        #pragma unroll
        for (int c = 0; c < 4; ++c) {
            float x = X[c], p = P[c], y0 = Y0[c], z0 = Z0[c];
            float u = al * U[c], v = al * V[c];
            float y  = x + an * (y0 - x) + u;
            float dz = an * (z0 - p);
            float z  = x + an * (p - x) + dz + u + v;
            float zm = z - y;
            float t  = fabsf(zm) - 0.1f;
            float pr = (t > 0.f) ? copysignf(t, zm) : 0.f;
            float xn = x + (pr - z) + dz;
            XN[c] = xn; PR[c] = pr; YY[c] = y; ZZ[c] = z;
            float e1 = pr - y; r += e1 * e1;
            float e2 = xn - z; d += e2 * e2;
        }
        S4[base] = xn4; S4[base + 144] = pr4; S4[base + 288] = yy4; S4[base + 432] = zz4;
    }
    #pragma unroll
    for (int off = 32; off > 0; off >>= 1) {
        r += __shfl_down(r, off);
        d += __shfl_down(d, off);
    }
    __shared__ float sr[4], sd[4];
    int lane = threadIdx.x & 63, wid = threadIdx.x >> 6;
    if (lane == 0) { sr[wid] = r; sd[wid] = d; }
    __syncthreads();
    if (threadIdx.x == 0) {
        int bk = blockIdx.x & 31;
        atomicAdd(&redcur[bk],      sr[0] + sr[1] + sr[2] + sr[3]);
        atomicAdd(&redcur[32 + bk], sd[0] + sd[1] + sd[2] + sd[3]);
    }
}

// ---------- bf16 MFMA GEMM: C[M,N] = A[M,K] @ Wt[N,K]^T + bias ---------------
// 256 thr = 4 waves (1 M x 4 N), tile 32x128, BK=32, 16x16x32 bf16 MFMA.
// AF32: A is f32, converted to bf16 during LDS staging (VGPR path).
// NB: n-blocks per m-row; 1-D grid with same-A blocks adjacent for L2 reuse.
template <bool AF32, bool RELU, bool QACC, bool BF16OUT, int NB>
__global__ __launch_bounds__(256) void k_gemm(const void* __restrict__ Avoid,
                                              const ushort* __restrict__ Wt,
                                              const float* __restrict__ bias,
                                              void* __restrict__ Cout,
                                              int K, int N,
                                              float* __restrict__ qbuck) {
    __shared__ ushort As[32 * 32];
    __shared__ ushort Bs[128 * 32];
    const int tid = threadIdx.x;
    const int bx = blockIdx.x;
    const int m0 = (bx / NB) * 32;
    const int n0 = (bx % NB) * 128;
    const int wave = tid >> 6, lane = tid & 63;
    const int wn = wave * 32;
    const int lm = lane & 15, quad = lane >> 4;

    f32x4 acc[2][2];
    #pragma unroll
    for (int i = 0; i < 2; ++i)
        #pragma unroll
        for (int j = 0; j < 2; ++j) acc[i][j] = (f32x4){0.f, 0.f, 0.f, 0.f};

    for (int k0 = 0; k0 < K; k0 += 32) {
        if (AF32) {
            const float* A = (const float*)Avoid;
            // 32 rows x 8 float4-cols = 256 slots, 1 per thread
            int rr = tid >> 3, kq = (tid & 7) << 2;
            float4 av = *(const float4*)(A + (size_t)(m0 + rr) * K + k0 + kq);
            ushort4 b4;
            b4.x = f2bf(av.x); b4.y = f2bf(av.y); b4.z = f2bf(av.z); b4.w = f2bf(av.w);
            *(ushort4*)&As[rr * 32 + kq] = b4;
        } else {
            const ushort* A = (const ushort*)Avoid;
            if (tid < 128) {                         // 32 rows x 4 chunks16
                int rr = tid >> 2, kq = (tid & 3) << 3;
                gload_lds16(A + (size_t)(m0 + rr) * K + k0 + kq, &As[tid * 8]);
            }
        }
        #pragma unroll
        for (int c = tid; c < 512; c += 256) {       // B: 128 rows x 4 chunks16
            int rr = c >> 2, kq = (c & 3) << 3;
            gload_lds16(Wt + (size_t)(n0 + rr) * K + k0 + kq, &Bs[c * 8]);
        }
        __syncthreads();
        s16x8 af[2], bfr[2];
        #pragma unroll
        for (int i = 0; i < 2; ++i)
            af[i] = *(const s16x8*)&As[(i * 16 + lm) * 32 + quad * 8];
        #pragma unroll
        for (int j = 0; j < 2; ++j)
            bfr[j] = *(const s16x8*)&Bs[(wn + j * 16 + lm) * 32 + quad * 8];
        #pragma unroll
        for (int i = 0; i < 2; ++i)
            #pragma unroll
            for (int j = 0; j < 2; ++j)
                acc[i][j] = __builtin_amdgcn_mfma_f32_16x16x32_bf16(af[i], bfr[j], acc[i][j], 0, 0, 0);
        __syncthreads();
    }

    float q = 0.f;
    #pragma unroll
    for (int j = 0; j < 2; ++j) {
        int col = n0 + wn + j * 16 + lm;
        float bb = bias[col];
        #pragma unroll
        for (int i = 0; i < 2; ++i) {
            #pragma unroll
            for (int rr = 0; rr < 4; ++rr) {
                int row = m0 + i * 16 + quad * 4 + rr;
                float c = acc[i][j][rr] + bb;
                if (RELU) c = fmaxf(c, 0.f);
                if (QACC) q += c * c;
                if (BF16OUT) ((ushort*)Cout)[(size_t)row * N + col] = f2bf(c);
                else         ((float*)Cout)[(size_t)row * N + col] = c;
            }
        }
    }
    if (QACC) {
        #pragma unroll
        for (int off = 32; off > 0; off >>= 1) q += __shfl_down(q, off);
        __shared__ float sq[4];
        if (lane == 0) sq[wave] = q;
        __syncthreads();
        if (tid == 0) atomicAdd(&qbuck[bx & 31], sq[0] + sq[1] + sq[2] + sq[3]);
    }
}

// ---------- finish: p_final = S chunk 1; block 0 folds residuals -------------
__global__ __launch_bounds__(256) void k_finish(const float4* __restrict__ S4,
                                                float4* __restrict__ out4,
                                                const float* __restrict__ red,
                                                float* __restrict__ res_out,
                                                int total4 /* B*144 */) {
    int i = blockIdx.x * 256 + threadIdx.x;
    if (blockIdx.x == 0 && threadIdx.x < TS) {
        const float* rb = red + (threadIdx.x + 1) * 96;
        float s = 0.f;
        #pragma unroll
        for (int c = 0; c < 32; ++c) s += rb[c];
        res_out[threadIdx.x] = sqrtf(s + 1e-12f);
    }
    if (i >= total4) return;
    int sample = i / 144;
    int j = i - sample * 144;
    out4[i] = S4[(size_t)sample * 576 + 144 + j];
}

extern "C" void kernel_launch(void* const* d_in, const int* in_sizes, int n_in,
                              void* d_out, int out_size, void* d_ws, size_t ws_size,
                              hipStream_t stream) {
    const float* noisy = (const float*)d_in[0];
    const float* W1 = (const float*)d_in[1];
    const float* b1 = (const float*)d_in[2];
    const float* W2 = (const float*)d_in[3];
    const float* b2 = (const float*)d_in[4];
    const float* W3 = (const float*)d_in[5];
    const float* b3 = (const float*)d_in[6];
    const int B = in_sizes[0] / 64;   // 16384

    // workspace layout (total ~245 MB)
    float*  S   = (float*)d_ws;                         // [B,2304] f32
    float*  uv  = S + (size_t)B * INF;                  // [B,1152] f32
    ushort* h1  = (ushort*)(uv + (size_t)B * OUTF);     // [B,256]  bf16
    ushort* h2  = h1 + (size_t)B * HID;                 // [B,256]  bf16
    ushort* Wt1 = h2 + (size_t)B * HID;                 // [256,2304] bf16
    ushort* Wt2 = Wt1 + (size_t)HID * INF;              // [256,256]  bf16
    ushort* Wt3 = Wt2 + (size_t)HID * HID;              // [1152,256] bf16
    float*  red = (float*)(Wt3 + (size_t)OUTF * HID);   // 21 slots x 96 scalars

    float* p_out   = (float*)d_out;                     // [B,576]
    float* res_out = p_out + (size_t)B * SVEC;          // [20]

    const int tot4 = B * 144;                           // float4 units per chunk-slot

    k_init<<<(tot4 * 4 + 255) / 256, 256, 0, stream>>>((float4*)S, (const float4*)noisy, tot4 * 4);
    k_zero<<<(21 * 96 + 127) / 128, 128, 0, stream>>>(red, 21 * 96);
    k_zero<<<((B * OUTF) + 127) / 128, 128, 0, stream>>>(uv, B * OUTF);
    k_wt<<<(HID * INF + 255) / 256, 256, 0, stream>>>(W1, Wt1, INF, HID, HID * INF);
    k_wt<<<(HID * HID + 255) / 256, 256, 0, stream>>>(W2, Wt2, HID, HID, HID * HID);
    k_wt<<<(OUTF * HID + 255) / 256, 256, 0, stream>>>(W3, Wt3, HID, OUTF, OUTF * HID);

    const int g1 = (B / 32) * 2;    // 1024 blocks (NB=2)
    const int g2 = (B / 32) * 2;    // 1024 blocks (NB=2)
    const int g3 = (B / 32) * 9;    // 4608 blocks (NB=9)

    for (int n = 0; n < TS; ++n) {
        float an = (float)n / ((float)n + 3.0f);
        float* redprev = red + (size_t)n * 96;        // step n-1's slot (slot 0 = zeros)
        float* redcur  = red + (size_t)(n + 1) * 96;
        k_fbs<<<(tot4 + 255) / 256, 256, 0, stream>>>((float4*)S, (const float4*)uv,
                                                      redprev, redcur, an, tot4);
        k_gemm<true,  true,  false, true,  2><<<g1, 256, 0, stream>>>(S,  Wt1, b1, h1, INF, HID, nullptr);
        k_gemm<false, true,  false, true,  2><<<g2, 256, 0, stream>>>(h1, Wt2, b2, h2, HID, HID, nullptr);
        k_gemm<false, false, true,  false, 9><<<g3, 256, 0, stream>>>(h2, Wt3, b3, uv, HID, OUTF, redcur + 64);
    }
    k_finish<<<(tot4 + 255) / 256, 256, 0, stream>>>((const float4*)S, (float4*)p_out,
                                                     red, res_out, tot4);
}

// Round 5
// 4489.575 us; speedup vs baseline: 4.2222x; 1.0296x over previous
//
#include <hip/hip_runtime.h>
#include <math.h>

constexpr int SVEC = 576;    // N_CH * 64
constexpr int INF  = 2304;   // 4 * SVEC
constexpr int HID  = 256;
constexpr int OUTF = 1152;   // 2 * SVEC
constexpr int TS   = 20;
constexpr int MR   = 16;     // samples per fused block
constexpr int APAD = 2312;   // 2304 + 8 ushorts: LDS row pad (2-way-free frag reads)

// ---------- helpers ----------------------------------------------------------
__device__ __forceinline__ ushort f2bf(float f) {    // RNE f32->bf16
    union { float f; unsigned u; } a; a.f = f;
    unsigned r = a.u + 0x7fff + ((a.u >> 16) & 1);
    return (ushort)(r >> 16);
}
__device__ __forceinline__ float bf2f(ushort b) {
    union { unsigned u; float f; } a; a.u = ((unsigned)b) << 16;
    return a.f;
}

__device__ __forceinline__ void gload_lds16(const void* g, void* l) {
    __builtin_amdgcn_global_load_lds(
        (const __attribute__((address_space(1))) void*)g,
        (__attribute__((address_space(3))) void*)l, 16, 0, 0);
}

typedef short  s16x8 __attribute__((ext_vector_type(8)));
typedef float  f32x4 __attribute__((ext_vector_type(4)));

// ---------- init: S = [x|p|y|z] all = [noisy, 0...] --------------------------
__global__ __launch_bounds__(256) void k_init(float4* __restrict__ S4,
                                              const float4* __restrict__ noisy4,
                                              int total4) {
    int i = blockIdx.x * 256 + threadIdx.x;
    if (i >= total4) return;
    int sample = i / 576;
    int j = i - sample * 576;
    int jc = j % 144;
    float4 v = make_float4(0.f, 0.f, 0.f, 0.f);
    if (jc < 16) v = noisy4[sample * 16 + jc];
    S4[i] = v;
}

__global__ __launch_bounds__(128) void k_zero(float* __restrict__ p, int n) {
    int i = blockIdx.x * 128 + threadIdx.x;
    if (i < n) p[i] = 0.f;
}

// ---------- weight transpose + bf16 convert: Wt[n*K+k] = W[k*N+n] ------------
__global__ __launch_bounds__(256) void k_wt(const float* __restrict__ W,
                                            ushort* __restrict__ Wt,
                                            int K, int N, int total) {
    int i = blockIdx.x * 256 + threadIdx.x;
    if (i >= total) return;
    int n = i / K, k = i - n * K;
    Wt[i] = f2bf(W[(size_t)k * N + n]);
}

// ---------- fused FBS + GEMM1 ------------------------------------------------
// Per block: MR=16 samples. Phase 1: FBS update in f32 (S in-place), bf16
// A-tile into LDS, r/d reductions. Phase 2: 16x256 GEMM vs Wt1 (B-frags direct
// from global/L2, no barriers in K-loop), bias+ReLU, bf16 h1 out.
__global__ __launch_bounds__(256) void k_fused1(float4* __restrict__ S4,
                                                const ushort4* __restrict__ uvb,
                                                const float* __restrict__ redprev,
                                                float* __restrict__ redcur,
                                                const ushort* __restrict__ Wt1,
                                                const float* __restrict__ bias,
                                                ushort* __restrict__ h1,
                                                float an) {
    __shared__ ushort A[MR][APAD];
    __shared__ float s_alpha;
    __shared__ float sr[4], sd[4];
    const int tid = threadIdx.x;
    const int m0 = blockIdx.x * MR;
    const int lane = tid & 63, wave = tid >> 6;

    // ---- alpha from previous step's buckets (slot 0 = zeros -> alpha 0)
    if (tid < 64) {
        float v = (tid < 32) ? redprev[32 + tid] : redprev[64 + (tid - 32)];
        #pragma unroll
        for (int off = 16; off > 0; off >>= 1) v += __shfl_down(v, off);
        float Q = __shfl(v, 32);
        if (tid == 0) {
            float Qs = 1.5f * Q + 1e-12f;
            float b  = 0.99f * fmaxf(v, 0.f);
            s_alpha = sqrtf(fminf(b / Qs, 1.f));
        }
    }
    __syncthreads();
    const float al = s_alpha;

    // ---- phase 1: FBS on 16 samples (2304 float4-slots, 9 per thread)
    float r = 0.f, d = 0.f;
    #pragma unroll
    for (int it = 0; it < 9; ++it) {
        int s = tid + it * 256;               // 0..2303
        int smp = s / 144, j = s - smp * 144; // j: float4 index within chunk
        size_t base = (size_t)(m0 + smp) * 576 + j;
        float4 x4 = S4[base], p4 = S4[base + 144];
        float4 y4 = S4[base + 288], z4 = S4[base + 432];
        size_t ub = (size_t)(m0 + smp) * 288 + j;
        ushort4 ubv = uvb[ub], vbv = uvb[ub + 144];
        float4 xn4, pr4, yy4, zz4;
        ushort4 bxn, bpr, byy, bzz;
        const float* X = (const float*)&x4;  const float* P = (const float*)&p4;
        const float* Y0 = (const float*)&y4; const float* Z0 = (const float*)&z4;
        const ushort* UB = (const ushort*)&ubv; const ushort* VB = (const ushort*)&vbv;
        float* XN = (float*)&xn4; float* PR = (float*)&pr4;
        float* YY = (float*)&yy4; float* ZZ = (float*)&zz4;
        ushort* BX = (ushort*)&bxn; ushort* BP = (ushort*)&bpr;
        ushort* BY = (ushort*)&byy; ushort* BZ = (ushort*)&bzz;
        #pragma unroll
        for (int c = 0; c < 4; ++c) {
            float x = X[c], p = P[c], y0 = Y0[c], z0 = Z0[c];
            float u = al * bf2f(UB[c]), v = al * bf2f(VB[c]);
            float y  = x + an * (y0 - x) + u;
            float dz = an * (z0 - p);
            float z  = x + an * (p - x) + dz + u + v;
            float zm = z - y;
            float t  = fabsf(zm) - 0.1f;
            float pr = (t > 0.f) ? copysignf(t, zm) : 0.f;
            float xn = x + (pr - z) + dz;
            XN[c] = xn; PR[c] = pr; YY[c] = y; ZZ[c] = z;
            BX[c] = f2bf(xn); BP[c] = f2bf(pr); BY[c] = f2bf(y); BZ[c] = f2bf(z);
            float e1 = pr - y; r += e1 * e1;
            float e2 = xn - z; d += e2 * e2;
        }
        S4[base] = xn4; S4[base + 144] = pr4;
        S4[base + 288] = yy4; S4[base + 432] = zz4;
        *(ushort4*)&A[smp][       j * 4] = bxn;
        *(ushort4*)&A[smp][ 576 + j * 4] = bpr;
        *(ushort4*)&A[smp][1152 + j * 4] = byy;
        *(ushort4*)&A[smp][1728 + j * 4] = bzz;
    }
    #pragma unroll
    for (int off = 32; off > 0; off >>= 1) {
        r += __shfl_down(r, off);
        d += __shfl_down(d, off);
    }
    if (lane == 0) { sr[wave] = r; sd[wave] = d; }
    __syncthreads();                           // phase barrier (A-tile + sr/sd)
    if (tid == 0) {
        int bk = blockIdx.x & 31;
        atomicAdd(&redcur[bk],      sr[0] + sr[1] + sr[2] + sr[3]);
        atomicAdd(&redcur[32 + bk], sd[0] + sd[1] + sd[2] + sd[3]);
    }

    // ---- phase 2: GEMM 16 x 256, K = 2304; wave covers 64 cols
    const int wn = wave * 64;
    const int lm = lane & 15, quad = lane >> 4;
    f32x4 acc[4];
    #pragma unroll
    for (int j = 0; j < 4; ++j) acc[j] = (f32x4){0.f, 0.f, 0.f, 0.f};
    const ushort* W0 = Wt1 + (size_t)(wn + lm) * INF;
    #pragma unroll 2
    for (int k0 = 0; k0 < INF; k0 += 32) {
        s16x8 af = *(const s16x8*)&A[lm][k0 + quad * 8];
        s16x8 bf0 = *(const s16x8*)(W0 +  0 * INF + k0 + quad * 8);
        s16x8 bf1 = *(const s16x8*)(W0 + 16 * INF + k0 + quad * 8);
        s16x8 bf2 = *(const s16x8*)(W0 + 32 * INF + k0 + quad * 8);
        s16x8 bf3 = *(const s16x8*)(W0 + 48 * INF + k0 + quad * 8);
        acc[0] = __builtin_amdgcn_mfma_f32_16x16x32_bf16(af, bf0, acc[0], 0, 0, 0);
        acc[1] = __builtin_amdgcn_mfma_f32_16x16x32_bf16(af, bf1, acc[1], 0, 0, 0);
        acc[2] = __builtin_amdgcn_mfma_f32_16x16x32_bf16(af, bf2, acc[2], 0, 0, 0);
        acc[3] = __builtin_amdgcn_mfma_f32_16x16x32_bf16(af, bf3, acc[3], 0, 0, 0);
    }
    #pragma unroll
    for (int j = 0; j < 4; ++j) {
        int col = wn + j * 16 + lm;
        float bb = bias[col];
        #pragma unroll
        for (int rr = 0; rr < 4; ++rr) {
            int row = m0 + quad * 4 + rr;
            float c = fmaxf(acc[j][rr] + bb, 0.f);
            h1[(size_t)row * HID + col] = f2bf(c);
        }
    }
}

// ---------- bf16 MFMA GEMM (layers 2/3): C = A @ Wt^T + bias -----------------
// 256 thr = 4 waves, tile 32x128, BK=32, 16x16x32 bf16 MFMA.
template <bool RELU, bool QACC, bool BF16OUT, int NB>
__global__ __launch_bounds__(256) void k_gemm(const ushort* __restrict__ A,
                                              const ushort* __restrict__ Wt,
                                              const float* __restrict__ bias,
                                              void* __restrict__ Cout,
                                              int K, int N,
                                              float* __restrict__ qbuck) {
    __shared__ ushort As[32 * 32];
    __shared__ ushort Bs[128 * 32];
    const int tid = threadIdx.x;
    const int bx = blockIdx.x;
    const int m0 = (bx / NB) * 32;
    const int n0 = (bx % NB) * 128;
    const int wave = tid >> 6, lane = tid & 63;
    const int wn = wave * 32;
    const int lm = lane & 15, quad = lane >> 4;

    f32x4 acc[2][2];
    #pragma unroll
    for (int i = 0; i < 2; ++i)
        #pragma unroll
        for (int j = 0; j < 2; ++j) acc[i][j] = (f32x4){0.f, 0.f, 0.f, 0.f};

    for (int k0 = 0; k0 < K; k0 += 32) {
        if (tid < 128) {                         // A: 32 rows x 4 chunks16
            int rr = tid >> 2, kq = (tid & 3) << 3;
            gload_lds16(A + (size_t)(m0 + rr) * K + k0 + kq, &As[tid * 8]);
        }
        #pragma unroll
        for (int c = tid; c < 512; c += 256) {   // B: 128 rows x 4 chunks16
            int rr = c >> 2, kq = (c & 3) << 3;
            gload_lds16(Wt + (size_t)(n0 + rr) * K + k0 + kq, &Bs[c * 8]);
        }
        __syncthreads();
        s16x8 af[2], bfr[2];
        #pragma unroll
        for (int i = 0; i < 2; ++i)
            af[i] = *(const s16x8*)&As[(i * 16 + lm) * 32 + quad * 8];
        #pragma unroll
        for (int j = 0; j < 2; ++j)
            bfr[j] = *(const s16x8*)&Bs[(wn + j * 16 + lm) * 32 + quad * 8];
        #pragma unroll
        for (int i = 0; i < 2; ++i)
            #pragma unroll
            for (int j = 0; j < 2; ++j)
                acc[i][j] = __builtin_amdgcn_mfma_f32_16x16x32_bf16(af[i], bfr[j], acc[i][j], 0, 0, 0);
        __syncthreads();
    }

    float q = 0.f;
    #pragma unroll
    for (int j = 0; j < 2; ++j) {
        int col = n0 + wn + j * 16 + lm;
        float bb = bias[col];
        #pragma unroll
        for (int i = 0; i < 2; ++i) {
            #pragma unroll
            for (int rr = 0; rr < 4; ++rr) {
                int row = m0 + i * 16 + quad * 4 + rr;
                float c = acc[i][j][rr] + bb;
                if (RELU) c = fmaxf(c, 0.f);
                if (QACC) q += c * c;
                if (BF16OUT) ((ushort*)Cout)[(size_t)row * N + col] = f2bf(c);
                else         ((float*)Cout)[(size_t)row * N + col] = c;
            }
        }
    }
    if (QACC) {
        #pragma unroll
        for (int off = 32; off > 0; off >>= 1) q += __shfl_down(q, off);
        __shared__ float sq[4];
        if (lane == 0) sq[wave] = q;
        __syncthreads();
        if (tid == 0) atomicAdd(&qbuck[bx & 31], sq[0] + sq[1] + sq[2] + sq[3]);
    }
}

// ---------- finish: p_final = S chunk 1; block 0 folds residuals -------------
__global__ __launch_bounds__(256) void k_finish(const float4* __restrict__ S4,
                                                float4* __restrict__ out4,
                                                const float* __restrict__ red,
                                                float* __restrict__ res_out,
                                                int total4) {
    int i = blockIdx.x * 256 + threadIdx.x;
    if (blockIdx.x == 0 && threadIdx.x < TS) {
        const float* rb = red + (threadIdx.x + 1) * 96;
        float s = 0.f;
        #pragma unroll
        for (int c = 0; c < 32; ++c) s += rb[c];
        res_out[threadIdx.x] = sqrtf(s + 1e-12f);
    }
    if (i >= total4) return;
    int sample = i / 144;
    int j = i - sample * 144;
    out4[i] = S4[(size_t)sample * 576 + 144 + j];
}

extern "C" void kernel_launch(void* const* d_in, const int* in_sizes, int n_in,
                              void* d_out, int out_size, void* d_ws, size_t ws_size,
                              hipStream_t stream) {
    const float* noisy = (const float*)d_in[0];
    const float* W1 = (const float*)d_in[1];
    const float* b1 = (const float*)d_in[2];
    const float* W2 = (const float*)d_in[3];
    const float* b2 = (const float*)d_in[4];
    const float* W3 = (const float*)d_in[5];
    const float* b3 = (const float*)d_in[6];
    const int B = in_sizes[0] / 64;   // 16384

    // workspace layout (~208 MB)
    float*  S   = (float*)d_ws;                         // [B,2304] f32
    ushort* h1  = (ushort*)(S + (size_t)B * INF);       // [B,256]  bf16
    ushort* h2  = h1 + (size_t)B * HID;                 // [B,256]  bf16
    ushort* Wt1 = h2 + (size_t)B * HID;                 // [256,2304] bf16
    ushort* Wt2 = Wt1 + (size_t)HID * INF;              // [256,256]  bf16
    ushort* Wt3 = Wt2 + (size_t)HID * HID;              // [1152,256] bf16
    float*  red = (float*)(Wt3 + (size_t)OUTF * HID);   // 21 slots x 96
    ushort* uv  = (ushort*)(red + 21 * 96);             // [B,1152] bf16

    float* p_out   = (float*)d_out;                     // [B,576]
    float* res_out = p_out + (size_t)B * SVEC;          // [20]

    const int tot4 = B * 144;

    k_init<<<(tot4 * 4 + 255) / 256, 256, 0, stream>>>((float4*)S, (const float4*)noisy, tot4 * 4);
    k_zero<<<(21 * 96 + 127) / 128, 128, 0, stream>>>(red, 21 * 96);
    k_zero<<<((B * OUTF / 2) + 127) / 128, 128, 0, stream>>>((float*)uv, B * OUTF / 2);
    k_wt<<<(HID * INF + 255) / 256, 256, 0, stream>>>(W1, Wt1, INF, HID, HID * INF);
    k_wt<<<(HID * HID + 255) / 256, 256, 0, stream>>>(W2, Wt2, HID, HID, HID * HID);
    k_wt<<<(OUTF * HID + 255) / 256, 256, 0, stream>>>(W3, Wt3, HID, OUTF, OUTF * HID);

    const int gf = B / MR;          // 1024 fused blocks
    const int g2 = (B / 32) * 2;    // 1024 blocks (NB=2)
    const int g3 = (B / 32) * 9;    // 4608 blocks (NB=9)

    for (int n = 0; n < TS; ++n) {
        float an = (float)n / ((float)n + 3.0f);
        float* redprev = red + (size_t)n * 96;
        float* redcur  = red + (size_t)(n + 1) * 96;
        k_fused1<<<gf, 256, 0, stream>>>((float4*)S, (const ushort4*)uv,
                                         redprev, redcur, Wt1, b1, h1, an);
        k_gemm<true,  false, true, 2><<<g2, 256, 0, stream>>>(h1, Wt2, b2, h2, HID, HID, nullptr);
        k_gemm<false, true,  true, 9><<<g3, 256, 0, stream>>>(h2, Wt3, b3, uv, HID, OUTF, redcur + 64);
    }
    k_finish<<<(tot4 + 255) / 256, 256, 0, stream>>>((const float4*)S, (float4*)p_out,
                                                     red, res_out, tot4);
}